// Round 2
// baseline (346.745 us; speedup 1.0000x reference)
//
#include <hip/hip_runtime.h>
#include <hip/hip_bf16.h>

typedef __hip_bfloat16 bf16;
typedef short bf16x8_t __attribute__((ext_vector_type(8)));  // 8 bf16 = 4 VGPRs
typedef float f32x4_t __attribute__((ext_vector_type(4)));

#define NTOK 8192
#define INF  1024
#define OUTF 1024
#define GS   8
#define KTOT (INF + INF * GS)  // 9216

union b8u { bf16 h[8]; bf16x8_t v; };
union b4u { bf16 h[4]; ushort2 v2[2]; };

// ---------------- prep: B only (A is now fused into the GEMM) ----------------------
// B[o,k] = bf16[ bw | sw*ss ], verbatim body of the verified prep_b path.
#define PB ((OUTF * INF * 2) / 256)   // 8192 blocks

__global__ __launch_bounds__(256) void prep_b(const float* __restrict__ bw,
                                              const float* __restrict__ sw,
                                              const float* __restrict__ ss,
                                              bf16* __restrict__ B) {
  const int tid = blockIdx.x * 256 + threadIdx.x;  // 0 .. OUTF*INF*2-1
  const int o = tid >> 11;                         // 2048 threads per o-row
  const int r = tid & 2047;                        // i*2 + half
  const float4 w4 = ((const float4*)sw)[tid];      // 4 of the 8 g-values of (o,i)
  const float sc = ss[tid >> 1];
  b4u r4;
  r4.h[0] = __float2bfloat16(w4.x * sc);
  r4.h[1] = __float2bfloat16(w4.y * sc);
  r4.h[2] = __float2bfloat16(w4.z * sc);
  r4.h[3] = __float2bfloat16(w4.w * sc);
  const size_t rowb = (size_t)o * KTOT;
  *(ushort2*)(B + rowb + INF + (size_t)r * 4)     = r4.v2[0];
  *(ushort2*)(B + rowb + INF + (size_t)r * 4 + 2) = r4.v2[1];
  if ((tid & 1) == 0)
    B[rowb + (r >> 1)] = __float2bfloat16(bw[tid >> 1]);
}

// ---------------- fused GEMM: C = A(x)[M,K] * B[N,K]^T, A computed on the fly ------
// BM=256 BN=128 BK=64, 512 thr = 8 waves (4Mx2N), per-wave 64x64. Grid 8x32 = 1/CU.
// A-tile (32 KB) is PRODUCED per K-tile: thread t owns chunks q=t+512d (d=0..3):
//   row = q>>3 = (t>>3)+64d, slot c = t&7; slot c holds k-chunk kc = c^(row&7)
//   (row&7 invariant under +64 -> one kc per thread). ds_write_b128 at byte q*16 =
//   contiguous 1KB/wave (conflict-free); swizzle lives in the CONTENT, so the
//   verified read path (swk0/swk1 fragments) is untouched.
// exp elimination: exp(-|x-g|) = min(e^-x * e^g, e^x * e^-g) -> 2 trans + 24 VALU
// per x-elem instead of 8 trans. Base region (kt<16): silu(x), identical expression
// to the old prep_a.
// Sync: ONE barrier per K-tile. produce(kt+1)->buf nxt, MFMA reads buf cur; B stage
// issues at iter top so boundary vmcnt(0) drains nothing in practice.
#define BM 256
#define BN 128
#define BK 64
#define NT (KTOT / BK)            // 144
#define NBASE (INF / BK)          // 16 base-region tiles
#define LDSA (BM * BK * 2)        // 32768 B
#define LDSB (BN * BK * 2)        // 16384 B
#define LDSBUF (LDSA + LDSB)      // 49152 B

__global__ __launch_bounds__(512) void gemm_fused(const float* __restrict__ x,
                                                  const bf16* __restrict__ Bm,
                                                  float* __restrict__ C) {
  __shared__ __align__(16) char smem[2 * LDSBUF];   // 96 KB double buffer
  const int t = threadIdx.x;
  const int lane = t & 63;
  const int w = t >> 6;            // wave 0..7
  const int wm = (w >> 1) * 64;
  const int wn = (w & 1) * 64;
  const int bc = blockIdx.x;       // N tile (0..7)
  const int br = blockIdx.y;       // M tile (0..31)

  // ---- B staging (verified global_load_lds machinery) ----
  const int srow = t >> 3;                         // 0..63
  const int scol = ((t & 7) ^ (srow & 7)) * 8;     // swizzled source k-offset
  const bf16* gB = Bm + (size_t)(bc * BN + srow) * KTOT + scol;
  const int wb = w * 1024;                         // wave-uniform LDS dest base

  // ---- A produce mapping ----
  const int arow0 = t >> 3;                        // + 64*d
  const int as = arow0 & 7;
  const int akc = (t & 7) ^ as;                    // k-chunk this thread computes
  const float* xrow = x + (size_t)(br * BM + arow0) * INF;

  const float EG[8]  = {0.36787944f, 0.47236655f, 0.60653066f, 0.77880078f,
                        1.0f, 1.28402542f, 1.64872127f, 2.11700002f};   // e^{g_v}
  const float EIG[8] = {2.71828183f, 2.11700002f, 1.64872127f, 1.28402542f,
                        1.0f, 0.77880078f, 0.60653066f, 0.47236655f};   // e^{-g_v}

  // ---- fragment addressing (verified, verbatim) ----
  const int frow = lane & 15;
  const int fk = (lane >> 4) * 8;
  const int fsw = frow & 7;
  const int swk0 = (((0  + fk) >> 3) ^ fsw) * 8;
  const int swk1 = (((32 + fk) >> 3) ^ fsw) * 8;

  f32x4_t acc[4][4] = {};
  float xbuf[32];   // base path: 32 x-values; spline path: uses [0..3]

#define STAGE_B2(buf_, kt_) do { \
    __builtin_amdgcn_global_load_lds( \
        (const __attribute__((address_space(1))) void*)(gB + (size_t)(kt_) * BK), \
        (__attribute__((address_space(3))) void*)(smem + (buf_) * LDSBUF + LDSA + wb), 16, 0, 0); \
    __builtin_amdgcn_global_load_lds( \
        (const __attribute__((address_space(1))) void*)(gB + (size_t)64 * KTOT + (size_t)(kt_) * BK), \
        (__attribute__((address_space(3))) void*)(smem + (buf_) * LDSBUF + LDSA + 8192 + wb), 16, 0, 0); \
  } while (0)

#define LOADX(ktp_) do { \
    if ((ktp_) < NBASE) { \
      const int k0_ = (ktp_) * BK; \
      _Pragma("unroll") \
      for (int d = 0; d < 4; ++d) { \
        const float* xp = xrow + (size_t)d * 64 * INF + k0_ + akc * 8; \
        const float4 a_ = ((const float4*)xp)[0]; \
        const float4 b_ = ((const float4*)xp)[1]; \
        xbuf[d*8+0]=a_.x; xbuf[d*8+1]=a_.y; xbuf[d*8+2]=a_.z; xbuf[d*8+3]=a_.w; \
        xbuf[d*8+4]=b_.x; xbuf[d*8+5]=b_.y; xbuf[d*8+6]=b_.z; xbuf[d*8+7]=b_.w; \
      } \
    } else { \
      const int ib_ = ((ktp_) - NBASE) * 8 + akc; \
      _Pragma("unroll") \
      for (int d = 0; d < 4; ++d) \
        xbuf[d] = xrow[(size_t)d * 64 * INF + ib_]; \
    } \
  } while (0)

#define PRODUCE(buf_, ktp_) do { \
    char* sAn = smem + (buf_) * LDSBUF; \
    if ((ktp_) < NBASE) { \
      _Pragma("unroll") \
      for (int d = 0; d < 4; ++d) { \
        b8u pk; \
        _Pragma("unroll") \
        for (int j = 0; j < 8; ++j) { \
          const float v_ = xbuf[d*8+j]; \
          pk.h[j] = __float2bfloat16(v_ / (1.0f + __expf(-v_))); \
        } \
        *(bf16x8_t*)(sAn + (t + 512 * d) * 16) = pk.v; \
      } \
    } else { \
      _Pragma("unroll") \
      for (int d = 0; d < 4; ++d) { \
        const float xv_ = xbuf[d]; \
        const float en_ = __expf(-xv_); \
        const float ep_ = __expf(xv_); \
        b8u pk; \
        _Pragma("unroll") \
        for (int j = 0; j < 8; ++j) \
          pk.h[j] = __float2bfloat16(fminf(en_ * EG[j], ep_ * EIG[j])); \
        *(bf16x8_t*)(sAn + (t + 512 * d) * 16) = pk.v; \
      } \
    } \
  } while (0)

  // prologue: tile 0 -> buf 0
  LOADX(0);
  STAGE_B2(0, 0);
  PRODUCE(0, 0);
  asm volatile("s_waitcnt vmcnt(0) lgkmcnt(0)" ::: "memory");
  __builtin_amdgcn_s_barrier();
  __builtin_amdgcn_sched_barrier(0);

  for (int kt = 0; kt < NT; ++kt) {
    const int cur = kt & 1;
    const int nxt = cur ^ 1;
    const bf16* sAc = (const bf16*)(smem + cur * LDSBUF);
    const bf16* sBc = (const bf16*)(smem + cur * LDSBUF + LDSA);
    const bool pf = (kt + 1) < NT;

    if (pf) { LOADX(kt + 1); STAGE_B2(nxt, kt + 1); }

    bf16x8_t af[4], bfr[4];
    // ---------------- phase 1: kk = 0 ----------------
    #pragma unroll
    for (int i = 0; i < 4; ++i)
      af[i] = *(const bf16x8_t*)(sAc + (wm + i * 16 + frow) * BK + swk0);
    #pragma unroll
    for (int j = 0; j < 4; ++j)
      bfr[j] = *(const bf16x8_t*)(sBc + (wn + j * 16 + frow) * BK + swk0);
    __builtin_amdgcn_s_setprio(1);
    #pragma unroll
    for (int i = 0; i < 4; ++i)
      #pragma unroll
      for (int j = 0; j < 4; ++j)
        acc[i][j] = __builtin_amdgcn_mfma_f32_16x16x32_bf16(af[i], bfr[j], acc[i][j], 0, 0, 0);
    __builtin_amdgcn_s_setprio(0);

    // produce next A-tile into the other buffer (overlaps with MFMA pipes)
    if (pf) PRODUCE(nxt, kt + 1);

    // ---------------- phase 2: kk = 32 ----------------
    #pragma unroll
    for (int i = 0; i < 4; ++i)
      af[i] = *(const bf16x8_t*)(sAc + (wm + i * 16 + frow) * BK + swk1);
    #pragma unroll
    for (int j = 0; j < 4; ++j)
      bfr[j] = *(const bf16x8_t*)(sBc + (wn + j * 16 + frow) * BK + swk1);
    __builtin_amdgcn_s_setprio(1);
    #pragma unroll
    for (int i = 0; i < 4; ++i)
      #pragma unroll
      for (int j = 0; j < 4; ++j)
        acc[i][j] = __builtin_amdgcn_mfma_f32_16x16x32_bf16(af[i], bfr[j], acc[i][j], 0, 0, 0);
    __builtin_amdgcn_s_setprio(0);

    // tile boundary: writes (lgkm) flushed + B stage (vm) done; one barrier per tile.
    asm volatile("s_waitcnt vmcnt(0) lgkmcnt(0)" ::: "memory");
    __builtin_amdgcn_s_barrier();
    __builtin_amdgcn_sched_barrier(0);
  }

  // epilogue: D mapping col = lane&15, row = (lane>>4)*4 + reg  [m89/m91]
  const int ccol = bc * BN + wn + frow;
  const int crow0 = br * BM + wm + (lane >> 4) * 4;
  #pragma unroll
  for (int i = 0; i < 4; ++i)
    #pragma unroll
    for (int r = 0; r < 4; ++r) {
      float* cp = C + (size_t)(crow0 + i * 16 + r) * OUTF + ccol;
      #pragma unroll
      for (int j = 0; j < 4; ++j)
        cp[j * 16] = acc[i][j][r];
    }
#undef STAGE_B2
#undef LOADX
#undef PRODUCE
}

// ---------------- fallback (ws too small): naive, correctness-only ----------------
__global__ __launch_bounds__(256) void naive_kern(const float* __restrict__ x,
                                                  const float* __restrict__ bw,
                                                  const float* __restrict__ sw,
                                                  const float* __restrict__ ss,
                                                  const float* __restrict__ grid,
                                                  float* __restrict__ out) {
  const int idx = blockIdx.x * 256 + threadIdx.x;  // n*OUTF + o
  const int o = idx & (OUTF - 1);
  const int n = idx >> 10;
  float acc = 0.f;
  for (int i = 0; i < INF; ++i) {
    const float xv = x[n * INF + i];
    const float s = xv / (1.f + __expf(-xv));
    acc += s * bw[o * INF + i];
    const float sc = ss[o * INF + i];
    #pragma unroll
    for (int g = 0; g < 8; ++g) {
      const float gv = grid[i * 8 + g];
      acc += __expf(-fabsf(xv - gv)) * sw[(size_t)(o * INF + i) * 8 + g] * sc;
    }
  }
  out[idx] = acc;
}

extern "C" void kernel_launch(void* const* d_in, const int* in_sizes, int n_in,
                              void* d_out, int out_size, void* d_ws, size_t ws_size,
                              hipStream_t stream) {
  const float* x    = (const float*)d_in[0];
  const float* bw   = (const float*)d_in[1];
  const float* sw   = (const float*)d_in[2];
  const float* ss   = (const float*)d_in[3];
  const float* grid = (const float*)d_in[4];
  float* out = (float*)d_out;

  const size_t needB = (size_t)OUTF * KTOT * sizeof(bf16);  // ~19 MB

  if (ws_size >= needB) {
    bf16* B = (bf16*)d_ws;
    prep_b<<<PB, 256, 0, stream>>>(bw, sw, ss, B);
    dim3 g(OUTF / BN, NTOK / BM);  // (8, 32) = 256 blocks = 1/CU
    gemm_fused<<<g, 512, 0, stream>>>(x, B, out);
  } else {
    naive_kern<<<(NTOK * OUTF) / 256, 256, 0, stream>>>(x, bw, sw, ss, grid, out);
  }
}

// Round 3
// 290.616 us; speedup vs baseline: 1.1931x; 1.1931x over previous
//
#include <hip/hip_runtime.h>
#include <hip/hip_bf16.h>

typedef __hip_bfloat16 bf16;
typedef short bf16x8_t __attribute__((ext_vector_type(8)));  // 8 bf16 = 4 VGPRs
typedef short s4_t __attribute__((ext_vector_type(4)));      // 4 bf16 = 8B
typedef float f32x4_t __attribute__((ext_vector_type(4)));

#define NTOK 8192
#define INF  1024
#define OUTF 1024
#define GS   8
#define KTOT (INF + INF * GS)  // 9216

union b8u { bf16 h[8]; bf16x8_t v; };
union b4u { bf16 h[4]; ushort2 v2[2]; };
union b4s { bf16 h[4]; s4_t v; };

// ---------------- fused prep v2 (one dispatch) -------------------------------------
// Blocks [0, PA): A[n,k] = bf16[ silu(x) | exp(-|x-g_v|) ], 4 elems/thread.
//   min-form (validated by R2 pass): exp(-|x-g|) = min(e^-x * e^g, e^x * e^-g)
//   -> 2 transcendentals/elem instead of 8. float4 x load; 8B silu store;
//   4x16B contiguous spline stores. Layout byte-identical to R0's prep_a output.
// Blocks [PA, PA+PB): B[o,k] = bf16[ bw | sw*ss ] -- R0 prep_b body VERBATIM.
#define PA ((NTOK * INF / 4) / 256)   // 8192 blocks (4 elems/thread)
#define PB ((OUTF * INF * 2) / 256)   // 8192 blocks

__global__ __launch_bounds__(256) void prep_fused(const float* __restrict__ x,
                                                  const float* __restrict__ bw,
                                                  const float* __restrict__ sw,
                                                  const float* __restrict__ ss,
                                                  bf16* __restrict__ A,
                                                  bf16* __restrict__ B) {
  const int b = blockIdx.x;
  if (b < PA) {
    const float EG[8]  = {0.36787944f, 0.47236655f, 0.60653066f, 0.77880078f,
                          1.0f, 1.28402542f, 1.64872127f, 2.11700002f};   // e^{g_v}
    const float EIG[8] = {2.71828183f, 2.11700002f, 1.64872127f, 1.28402542f,
                          1.0f, 0.77880078f, 0.60653066f, 0.47236655f};   // e^{-g_v}
    const int tid = b * 256 + threadIdx.x;      // 0 .. NTOK*INF/4-1
    const int qi = tid & 255;                   // i-quad within row; i = qi*4+j
    const int n = tid >> 8;
    const float4 x4 = ((const float4*)x)[tid];  // x[n*INF + qi*4 ..+3]
    const float xf[4] = {x4.x, x4.y, x4.z, x4.w};
    b4s sil;
    b8u kn[4];
    #pragma unroll
    for (int j = 0; j < 4; ++j) {
      const float xv = xf[j];
      const float en = __expf(-xv);
      const float ep = __expf(xv);
      sil.h[j] = __float2bfloat16(xv / (1.0f + en));   // SiLU (same expr as R0)
      #pragma unroll
      for (int g = 0; g < 8; ++g)
        kn[j].h[g] = __float2bfloat16(fminf(en * EG[g], ep * EIG[g]));
    }
    const size_t rowb = (size_t)n * KTOT;
    *(s4_t*)(A + rowb + qi * 4) = sil.v;                       // 8B aligned
    #pragma unroll
    for (int j = 0; j < 4; ++j)                                 // 4x16B contiguous
      *(bf16x8_t*)(A + rowb + INF + (size_t)(qi * 4 + j) * 8) = kn[j].v;
  } else {
    // ---- prep_b (verbatim, validated) ----
    const int tid = (b - PA) * 256 + threadIdx.x;  // 0 .. OUTF*INF*2-1
    const int o = tid >> 11;
    const int r = tid & 2047;
    const float4 w4 = ((const float4*)sw)[tid];
    const float sc = ss[tid >> 1];
    b4u r4;
    r4.h[0] = __float2bfloat16(w4.x * sc);
    r4.h[1] = __float2bfloat16(w4.y * sc);
    r4.h[2] = __float2bfloat16(w4.z * sc);
    r4.h[3] = __float2bfloat16(w4.w * sc);
    const size_t rowb = (size_t)o * KTOT;
    *(ushort2*)(B + rowb + INF + (size_t)r * 4)     = r4.v2[0];
    *(ushort2*)(B + rowb + INF + (size_t)r * 4 + 2) = r4.v2[1];
    if ((tid & 1) == 0)
      B[rowb + (r >> 1)] = __float2bfloat16(bw[tid >> 1]);
  }
}

// ---------------- GEMM: C[M,N] = A[M,K] * B[N,K]^T ---------------------------------
// R1 kernel (counted-vmcnt 3-ring, verified) with ONE change: XCD-aware (bc,br)
// remap. Default round-robin (xcd = lid%8) on the (8,32) grid put bc==xcd, i.e.
// every XCD streamed ALL of A (151MB) through its 4MB L2 -> 600MB HBM fetch,
// memory-bound at 3.8TB/s (R1: 648MB/3.84TB/s = 169us = measured dur).
// Remap: XCD j owns br in [4j, 4j+4) x all bc -> per-K-tile working set 256KB
// (fits L2), A fetched ~once from HBM, B dedupes in L3.
#define BM 256
#define BN 128
#define BK 64
#define NT (KTOT / BK)            // 144
#define LDSA (BM * BK * 2)        // 32768 B
#define LDSB (BN * BK * 2)        // 16384 B
#define LDSBUF (LDSA + LDSB)      // 49152 B

__global__ __launch_bounds__(512) void gemm_bt2(const bf16* __restrict__ A,
                                                const bf16* __restrict__ B,
                                                float* __restrict__ C) {
  __shared__ __align__(16) char smem[3 * LDSBUF];   // 144 KB ring
  const int t = threadIdx.x;
  const int lane = t & 63;
  const int w = t >> 6;            // wave 0..7
  const int wm = (w >> 1) * 64;    // 0,64,128,192
  const int wn = (w & 1) * 64;     // 0,64
  // XCD-aware remap (bijective on 0..255): xcd = lid&7 gets br 4*xcd..4*xcd+3, all bc.
  const int lid = blockIdx.y * 8 + blockIdx.x;     // linear id, x fastest
  const int br = (lid & 7) * 4 + ((lid >> 3) & 3); // M tile (0..31)
  const int bc = lid >> 5;                         // N tile (0..7)

  const int srow = t >> 3;                         // 0..63
  const int scol = ((t & 7) ^ (srow & 7)) * 8;     // swizzled source k-offset (elems)
  const bf16* gA = A + (size_t)(br * BM + srow) * KTOT + scol;
  const bf16* gB = B + (size_t)(bc * BN + srow) * KTOT + scol;
  const int wb = w * 1024;                         // wave's 64 lanes x 16B

  // fragment addressing (verbatim from verified kernel)
  const int frow = lane & 15;
  const int fk = (lane >> 4) * 8;
  const int fsw = frow & 7;
  const int swk0 = (((0  + fk) >> 3) ^ fsw) * 8;   // kk=0  swizzled elem offset
  const int swk1 = (((32 + fk) >> 3) ^ fsw) * 8;   // kk=32

  f32x4_t acc[4][4] = {};

#define STAGE_A(b_, i_, kt_) \
  __builtin_amdgcn_global_load_lds( \
      (const __attribute__((address_space(1))) void*)(gA + (size_t)(i_) * 64 * KTOT + (size_t)(kt_) * BK), \
      (__attribute__((address_space(3))) void*)(smem + (b_) * LDSBUF + (i_) * 8192 + wb), 16, 0, 0)
#define STAGE_B(b_, i_, kt_) \
  __builtin_amdgcn_global_load_lds( \
      (const __attribute__((address_space(1))) void*)(gB + (size_t)(i_) * 64 * KTOT + (size_t)(kt_) * BK), \
      (__attribute__((address_space(3))) void*)(smem + (b_) * LDSBUF + LDSA + (i_) * 8192 + wb), 16, 0, 0)

  // prologue: tile 0 -> buf0, tile 1 -> buf1 (12 loads in flight)
  STAGE_A(0, 0, 0); STAGE_A(0, 1, 0); STAGE_A(0, 2, 0); STAGE_A(0, 3, 0);
  STAGE_B(0, 0, 0); STAGE_B(0, 1, 0);
  STAGE_A(1, 0, 1); STAGE_A(1, 1, 1); STAGE_A(1, 2, 1); STAGE_A(1, 3, 1);
  STAGE_B(1, 0, 1); STAGE_B(1, 1, 1);
  asm volatile("s_waitcnt vmcnt(6)" ::: "memory");   // tile 0 resident
  __builtin_amdgcn_s_barrier();

  int cb = 0;
  for (int kt = 0; kt < NT; ++kt) {
    const bf16* sAc = (const bf16*)(smem + cb * LDSBUF);
    const bf16* sBc = (const bf16*)(smem + cb * LDSBUF + LDSA);
    const int pb = (cb == 0) ? 2 : cb - 1;           // (kt+2)%3
    const bool pf = kt < NT - 2;

    bf16x8_t af[4], bfr[4];

    // ---------------- phase 1: kk = 0 ----------------
    #pragma unroll
    for (int i = 0; i < 4; ++i)
      af[i] = *(const bf16x8_t*)(sAc + (wm + i * 16 + frow) * BK + swk0);
    #pragma unroll
    for (int j = 0; j < 4; ++j)
      bfr[j] = *(const bf16x8_t*)(sBc + (wn + j * 16 + frow) * BK + swk0);
    if (pf) { STAGE_A(pb, 0, kt + 2); STAGE_A(pb, 1, kt + 2); STAGE_A(pb, 2, kt + 2); }
    __builtin_amdgcn_s_barrier();
    asm volatile("s_waitcnt lgkmcnt(0)" ::: "memory");
    __builtin_amdgcn_sched_barrier(0);
    __builtin_amdgcn_s_setprio(1);
    #pragma unroll
    for (int i = 0; i < 4; ++i)
      #pragma unroll
      for (int j = 0; j < 4; ++j)
        acc[i][j] = __builtin_amdgcn_mfma_f32_16x16x32_bf16(af[i], bfr[j], acc[i][j], 0, 0, 0);
    __builtin_amdgcn_s_setprio(0);
    __builtin_amdgcn_s_barrier();

    // ---------------- phase 2: kk = 32 ----------------
    #pragma unroll
    for (int i = 0; i < 4; ++i)
      af[i] = *(const bf16x8_t*)(sAc + (wm + i * 16 + frow) * BK + swk1);
    #pragma unroll
    for (int j = 0; j < 4; ++j)
      bfr[j] = *(const bf16x8_t*)(sBc + (wn + j * 16 + frow) * BK + swk1);
    if (pf) { STAGE_A(pb, 3, kt + 2); STAGE_B(pb, 0, kt + 2); STAGE_B(pb, 1, kt + 2); }
    __builtin_amdgcn_s_barrier();
    asm volatile("s_waitcnt lgkmcnt(0)" ::: "memory");
    __builtin_amdgcn_sched_barrier(0);
    __builtin_amdgcn_s_setprio(1);
    #pragma unroll
    for (int i = 0; i < 4; ++i)
      #pragma unroll
      for (int j = 0; j < 4; ++j)
        acc[i][j] = __builtin_amdgcn_mfma_f32_16x16x32_bf16(af[i], bfr[j], acc[i][j], 0, 0, 0);
    __builtin_amdgcn_s_setprio(0);
    // tile boundary: counted wait — tile kt+1's loads are strictly older than the
    // 6 issued this iteration, so vmcnt(6) retires them without draining the pipe.
    if (pf) asm volatile("s_waitcnt vmcnt(6)" ::: "memory");
    else    asm volatile("s_waitcnt vmcnt(0)" ::: "memory");
    __builtin_amdgcn_s_barrier();

    cb = (cb == 2) ? 0 : cb + 1;
  }

  // epilogue: D mapping col = lane&15, row = (lane>>4)*4 + reg  [m89/m91]
  const int ccol = bc * BN + wn + frow;
  const int crow0 = br * BM + wm + (lane >> 4) * 4;
  #pragma unroll
  for (int i = 0; i < 4; ++i)
    #pragma unroll
    for (int r = 0; r < 4; ++r) {
      float* cp = C + (size_t)(crow0 + i * 16 + r) * OUTF + ccol;
      #pragma unroll
      for (int j = 0; j < 4; ++j)
        cp[j * 16] = acc[i][j][r];
    }
#undef STAGE_A
#undef STAGE_B
}

// ---------------- fallback (ws too small): naive, correctness-only ----------------
__global__ __launch_bounds__(256) void naive_kern(const float* __restrict__ x,
                                                  const float* __restrict__ bw,
                                                  const float* __restrict__ sw,
                                                  const float* __restrict__ ss,
                                                  const float* __restrict__ grid,
                                                  float* __restrict__ out) {
  const int idx = blockIdx.x * 256 + threadIdx.x;  // n*OUTF + o
  const int o = idx & (OUTF - 1);
  const int n = idx >> 10;
  float acc = 0.f;
  for (int i = 0; i < INF; ++i) {
    const float xv = x[n * INF + i];
    const float s = xv / (1.f + __expf(-xv));
    acc += s * bw[o * INF + i];
    const float sc = ss[o * INF + i];
    #pragma unroll
    for (int g = 0; g < 8; ++g) {
      const float gv = grid[i * 8 + g];
      acc += __expf(-fabsf(xv - gv)) * sw[(size_t)(o * INF + i) * 8 + g] * sc;
    }
  }
  out[idx] = acc;
}

extern "C" void kernel_launch(void* const* d_in, const int* in_sizes, int n_in,
                              void* d_out, int out_size, void* d_ws, size_t ws_size,
                              hipStream_t stream) {
  const float* x    = (const float*)d_in[0];
  const float* bw   = (const float*)d_in[1];
  const float* sw   = (const float*)d_in[2];
  const float* ss   = (const float*)d_in[3];
  const float* grid = (const float*)d_in[4];
  float* out = (float*)d_out;

  const size_t needA = (size_t)NTOK * KTOT * sizeof(bf16);  // ~151 MB
  const size_t needB = (size_t)OUTF * KTOT * sizeof(bf16);  // ~19 MB

  if (ws_size >= needA + needB) {
    bf16* A = (bf16*)d_ws;
    bf16* B = (bf16*)((char*)d_ws + needA);
    prep_fused<<<PA + PB, 256, 0, stream>>>(x, bw, sw, ss, A, B);
    dim3 g(OUTF / BN, NTOK / BM);  // (8, 32) = 256 blocks = 1/CU
    gemm_bt2<<<g, 512, 0, stream>>>(A, B, out);
  } else {
    naive_kern<<<(NTOK * OUTF) / 256, 256, 0, stream>>>(x, bw, sw, ss, grid, out);
  }
}